// Round 16
// baseline (274.935 us; speedup 1.0000x reference)
//
#include <hip/hip_runtime.h>
#include <hip/hip_bf16.h>

#define NN 50000
#define EE 800000
#define SCAN_B 196  // 196*256 = 50176 >= NN+1

typedef unsigned short u16;
typedef unsigned int u32;
typedef float f32x16 __attribute__((ext_vector_type(16)));
typedef short bf16x8_t __attribute__((ext_vector_type(8)));

__device__ __forceinline__ float bfu2f(u16 b) { return __builtin_bit_cast(float, ((u32)b) << 16); }
__device__ __forceinline__ float lo16(u32 d) { return __builtin_bit_cast(float, d << 16); }
__device__ __forceinline__ float hi16(u32 d) { return __builtin_bit_cast(float, d & 0xffff0000u); }
__device__ __forceinline__ u16 f2bfu(float f) {
    u32 u = __builtin_bit_cast(u32, f);
    u32 r = (u + 0x7fffu + ((u >> 16) & 1u)) >> 16;
    return (u16)r;
}
__device__ __forceinline__ u32 cvt_pk_bf16(float lo, float hi) {
    u32 r;
    asm("v_cvt_pk_bf16_f32 %0, %1, %2" : "=v"(r) : "v"(lo), "v"(hi));
    return r;
}

// ---------------------------------------------------------------------------
// k_prep: fused {histogram over dst} + {weight transpose for MFMA}.
// blocks [0,3125): hist (3125*256 == EE exactly). blocks [3125,3189): wprep.
// ---------------------------------------------------------------------------
__global__ __launch_bounds__(256) void k_prep(
    const int* __restrict__ eidx, int* __restrict__ deg,
    const float* __restrict__ Wscs, const float* __restrict__ Wscv,
    const float* __restrict__ W1s, const float* __restrict__ W1v,
    u16* __restrict__ wscsT, u16* __restrict__ wscvT,
    u16* __restrict__ w1sT, u16* __restrict__ w1vT)
{
    const int b = blockIdx.x;
    if (b < 3125) {
        int e = b * 256 + threadIdx.x;
        atomicAdd(&deg[eidx[e]], 1);
    } else {
        int i = (b - 3125) * 256 + threadIdx.x;
        if (i < 16384) {
            int u = i >> 9, v = (i >> 5) & 15, w = i & 31;
            wscsT[(u * 32 + w) * 16 + v] = f2bfu(Wscs[i]);
            wscvT[(u * 32 + w) * 16 + v] = f2bfu(Wscv[i]);
        }
        if (i < 1024) {
            int u = i >> 5, w = i & 31;
            w1sT[w * 32 + u] = f2bfu(W1s[i]);
            w1vT[w * 32 + u] = f2bfu(W1v[i]);
        }
    }
}

// ---------------------------------------------------------------------------
// two-phase parallel scan
// ---------------------------------------------------------------------------
__global__ __launch_bounds__(256) void k_scan1(const int* __restrict__ deg, int* __restrict__ bsum) {
    __shared__ int red[256];
    const int tid = threadIdx.x;
    int i = blockIdx.x * 256 + tid;
    int v = (i < NN) ? deg[i] : 0;
    red[tid] = v;
    __syncthreads();
    for (int off = 128; off > 0; off >>= 1) {
        if (tid < off) red[tid] += red[tid + off];
        __syncthreads();
    }
    if (tid == 0) bsum[blockIdx.x] = red[0];
}

__global__ __launch_bounds__(256) void k_scan2(
    const int* __restrict__ deg, const int* __restrict__ bsum, int* __restrict__ row_ptr)
{
    const int b = blockIdx.x;
    const int tid = threadIdx.x;
    __shared__ int pre[256];
    __shared__ int bpre;
    int pv = (tid < b) ? bsum[tid] : 0;  // b <= 195 < 256
    pre[tid] = pv;
    __syncthreads();
    for (int off = 128; off > 0; off >>= 1) {
        if (tid < off) pre[tid] += pre[tid + off];
        __syncthreads();
    }
    if (tid == 0) bpre = pre[0];
    __syncthreads();
    int i = b * 256 + tid;
    int v = (i < NN) ? deg[i] : 0;
    pre[tid] = v;
    __syncthreads();
    for (int off = 1; off < 256; off <<= 1) {
        int t = (tid >= off) ? pre[tid - off] : 0;
        __syncthreads();
        pre[tid] += t;
        __syncthreads();
    }
    int excl = pre[tid] - v;
    if (i <= NN) row_ptr[i] = bpre + excl;  // i==NN -> EE
}

// ---------------------------------------------------------------------------
// k1 tile body (verified r12 variant): one wave per 32-node tile.
// hsv interleaved per u: hsv[node*128 + u*4 + {0,1,2,3}] = {hs, hv0, hv1, hv2}.
// ---------------------------------------------------------------------------
__device__ __forceinline__ void k1_tile(
    int base, int l, u16* __restrict__ sh,
    const float* __restrict__ x, const float* __restrict__ h,
    const u16* __restrict__ wscsT, const u16* __restrict__ wscvT,
    const u16* __restrict__ w1sT, const u16* __restrict__ w1vT,
    u16* __restrict__ hsv, float* __restrict__ out)
{
    u32* sh32 = (u32*)sh;
    const int n = l & 31;
    const int hi = l >> 5;

    {
        int r = base + (l >> 1);
        if (r >= NN) r = NN - 1;
        const float* hp = h + (size_t)r * 128 + (l & 1) * 64;
        int nn = l >> 1;
        int cp0 = (l & 1) * 32;
#pragma unroll
        for (int q = 0; q < 16; q++) {
            float4 f = *(const float4*)(hp + q * 4);
            sh32[(cp0 + 2 * q + 0) * 32 + nn] = cvt_pk_bf16(f.x, f.y);
            sh32[(cp0 + 2 * q + 1) * 32 + nn] = cvt_pk_bf16(f.z, f.w);
        }
    }
    float xv0, xv1, xv2, xv3, xv4, xv5, xv6, xv7;
    {
        int r = base + n;
        if (r >= NN) r = NN - 1;
        const float* xp = x + (size_t)r * 16 + hi * 8;
        float4 a = *(const float4*)xp;
        float4 b = *(const float4*)(xp + 4);
        xv0 = a.x; xv1 = a.y; xv2 = a.z; xv3 = a.w;
        xv4 = b.x; xv5 = b.y; xv6 = b.z; xv7 = b.w;
    }
    __syncthreads();

    f32x16 accS, accX, accY, accZ;
#pragma unroll
    for (int i = 0; i < 16; i++) { accS[i] = 0.f; accX[i] = 0.f; accY[i] = 0.f; accZ[i] = 0.f; }

#define MK_A(A, s)                                                     \
    { union { u32 w[4]; bf16x8_t v; } t_;                              \
      t_.w[0] = cvt_pk_bf16((s) * xv0, (s) * xv1);                     \
      t_.w[1] = cvt_pk_bf16((s) * xv2, (s) * xv3);                     \
      t_.w[2] = cvt_pk_bf16((s) * xv4, (s) * xv5);                     \
      t_.w[3] = cvt_pk_bf16((s) * xv6, (s) * xv7);                     \
      A = t_.v; }

    const size_t boff = (size_t)n * 16 + hi * 8;
    bf16x8_t Bs = *(const bf16x8_t*)(wscsT + boff);
    bf16x8_t Bv = *(const bf16x8_t*)(wscvT + boff);
#pragma unroll 2
    for (int u = 0; u < 32; u++) {
        bf16x8_t BsN, BvN;
        if (u < 31) {
            BsN = *(const bf16x8_t*)(wscsT + (size_t)(u + 1) * 512 + boff);
            BvN = *(const bf16x8_t*)(wscvT + (size_t)(u + 1) * 512 + boff);
        }
        float hsu = bfu2f(sh[(u >> 1) * 64 + n * 2 + (u & 1)]);
        int c = 32 + 3 * u;
        float hx = bfu2f(sh[(c >> 1) * 64 + n * 2 + (c & 1)]);
        float hy = bfu2f(sh[((c + 1) >> 1) * 64 + n * 2 + ((c + 1) & 1)]);
        float hz = bfu2f(sh[((c + 2) >> 1) * 64 + n * 2 + ((c + 2) & 1)]);
        bf16x8_t A;
        MK_A(A, hsu); accS = __builtin_amdgcn_mfma_f32_32x32x16_bf16(A, Bs, accS, 0, 0, 0);
        MK_A(A, hx);  accX = __builtin_amdgcn_mfma_f32_32x32x16_bf16(A, Bv, accX, 0, 0, 0);
        MK_A(A, hy);  accY = __builtin_amdgcn_mfma_f32_32x32x16_bf16(A, Bv, accY, 0, 0, 0);
        MK_A(A, hz);  accZ = __builtin_amdgcn_mfma_f32_32x32x16_bf16(A, Bv, accZ, 0, 0, 0);
        Bs = BsN; Bv = BvN;
    }
#undef MK_A

    const float inv_sc = 0.04419417382415922f;  // 1/sqrt(512)
#pragma unroll
    for (int r = 0; r < 16; r++) {
        int node2 = base + ((r & 3) + 8 * (r >> 2) + 4 * hi);
        if (node2 < NN) {
            float* op = out + (size_t)node2 * 128;
            op[n] = accS[r] * inv_sc;
            op[32 + n * 3 + 0] = accX[r] * inv_sc;
            op[32 + n * 3 + 1] = accY[r] * inv_sc;
            op[32 + n * 3 + 2] = accZ[r] * inv_sc;
        }
    }

    const float inv_m = 0.17677669529663687f;  // 1/sqrt(32)
    {
        f32x16 aw;
#pragma unroll
        for (int i = 0; i < 16; i++) aw[i] = 0.f;
#pragma unroll
        for (int k0 = 0; k0 < 2; k0++) {
            union { u32 w[4]; bf16x8_t v; } A;
#pragma unroll
            for (int q = 0; q < 4; q++)
                A.w[q] = sh32[(8 * k0 + 4 * hi + q) * 32 + n];
            bf16x8_t B = *(const bf16x8_t*)(w1sT + n * 32 + 16 * k0 + 8 * hi);
            aw = __builtin_amdgcn_mfma_f32_32x32x16_bf16(A.v, B, aw, 0, 0, 0);
        }
#pragma unroll
        for (int r = 0; r < 16; r++) {
            int node2 = base + ((r & 3) + 8 * (r >> 2) + 4 * hi);
            if (node2 < NN) hsv[(size_t)node2 * 128 + n * 4] = f2bfu(aw[r] * inv_m);
        }
    }
#pragma unroll
    for (int m = 0; m < 3; m++) {
        f32x16 aw;
#pragma unroll
        for (int i = 0; i < 16; i++) aw[i] = 0.f;
#pragma unroll
        for (int k0 = 0; k0 < 2; k0++) {
            union { u32 w[4]; bf16x8_t v; } A;
#pragma unroll
            for (int j = 0; j < 8; j += 2) {
                int u0 = 16 * k0 + 8 * hi + j;
                int c0 = 32 + 3 * u0 + m, c1 = c0 + 3;
                u16 a = sh[(c0 >> 1) * 64 + n * 2 + (c0 & 1)];
                u16 b = sh[(c1 >> 1) * 64 + n * 2 + (c1 & 1)];
                A.w[j >> 1] = (u32)a | ((u32)b << 16);
            }
            bf16x8_t B = *(const bf16x8_t*)(w1vT + n * 32 + 16 * k0 + 8 * hi);
            aw = __builtin_amdgcn_mfma_f32_32x32x16_bf16(A.v, B, aw, 0, 0, 0);
        }
#pragma unroll
        for (int r = 0; r < 16; r++) {
            int node2 = base + ((r & 3) + 8 * (r >> 2) + 4 * hi);
            if (node2 < NN) hsv[(size_t)node2 * 128 + n * 4 + 1 + m] = f2bfu(aw[r] * inv_m);
        }
    }
}

// ---------------------------------------------------------------------------
// k2a1: fused {k2a edge MLP + CSR scatter} (blocks [0,3125)) and
//       {k1 MFMA node prep} (blocks [3125,3516): 4 waves x 4 tiles each).
// ---------------------------------------------------------------------------
__global__ __launch_bounds__(256) void k2a1(
    const float* __restrict__ emb, const float* __restrict__ esh,
    const int* __restrict__ eidx, const float* __restrict__ fc1,
    const int* __restrict__ row_ptr, int* __restrict__ cursor,
    u32* __restrict__ edata,
    const float* __restrict__ x, const float* __restrict__ h,
    const u16* __restrict__ wscsT, const u16* __restrict__ wscvT,
    const u16* __restrict__ w1sT, const u16* __restrict__ w1vT,
    u16* __restrict__ hsv, float* __restrict__ out)
{
    __shared__ float sfc1[64];
    __shared__ __align__(16) u16 shh[4][4096];  // 8KB per wave (32KB)
    const int b = blockIdx.x;
    const int tid = threadIdx.x;
    if (b < 3125) {
        if (tid < 64) sfc1[tid] = fc1[tid];
        __syncthreads();
        int e = b * 256 + tid;  // 3125*256 == EE
        const float invb = 0.3535533905932738f;  // 1/sqrt(8)
        float4 ea = *(const float4*)(emb + (size_t)e * 8);
        float4 eb = *(const float4*)(emb + (size_t)e * 8 + 4);
        float em[8] = {ea.x, ea.y, ea.z, ea.w, eb.x, eb.y, eb.z, eb.w};
        float z[8];
#pragma unroll
        for (int k = 0; k < 8; k++) {
            float t = 0.f;
#pragma unroll
            for (int j = 0; j < 8; j++) t += em[j] * sfc1[j * 8 + k];
            t *= invb;
            z[k] = (t / (1.f + __expf(-t))) * invb;  // fold 1/sqrt(HID)
        }
        float4 sh = *(const float4*)(esh + (size_t)e * 4);
        int dst = eidx[e], src = eidx[EE + e];
        int p = atomicAdd(&cursor[dst], 1);
        size_t slot = (size_t)row_ptr[dst] + p;
        u32* wp = edata + slot * 8;
        uint4 A, B;
        A.x = cvt_pk_bf16(z[0], z[1]);
        A.y = cvt_pk_bf16(z[2], z[3]);
        A.z = cvt_pk_bf16(z[4], z[5]);
        A.w = cvt_pk_bf16(z[6], z[7]);
        B.x = cvt_pk_bf16(sh.x, sh.y);
        B.y = cvt_pk_bf16(sh.z, sh.w);
        B.z = ((u32)src) << 8;  // byte offset of hsv row (128 u16 = 256 B)
        B.w = 0;
        *(uint4*)wp = A;
        *(uint4*)(wp + 4) = B;
    } else {
        const int wv = tid >> 6, l = tid & 63;
        int tile = (b - 3125) * 4 + wv;  // up to 1563; tile 1563 fully clamped
        k1_tile(tile * 32, l, shh[wv], x, h, wscsT, wscvT, w1sT, w1vT, hsv, out);
    }
}

// ---------------------------------------------------------------------------
// K2b: gather + aggregate + fused output transform. One wave per dst node.
// Single uint2 gather per edge (interleaved hsv); branch-free epilogue.
// ---------------------------------------------------------------------------
__device__ __forceinline__ void edge_body(
    const u32* __restrict__ r, const char* __restrict__ hlane,
    const float* fcs, const float* fcv, bool lo,
    float& acc_s, float& av0, float& av1, float& av2)
{
    uint4 A = *(const uint4*)r;
    uint4 B = *(const uint4*)(r + 4);
    float ws_ = lo16(A.x) * fcs[0] + hi16(A.x) * fcs[1] + lo16(A.y) * fcs[2] + hi16(A.y) * fcs[3]
              + lo16(A.z) * fcs[4] + hi16(A.z) * fcs[5] + lo16(A.w) * fcs[6] + hi16(A.w) * fcs[7];
    float wv_ = lo16(A.x) * fcv[0] + hi16(A.x) * fcv[1] + lo16(A.y) * fcv[2] + hi16(A.y) * fcv[3]
              + lo16(A.z) * fcv[4] + hi16(A.z) * fcv[5] + lo16(A.w) * fcv[6] + hi16(A.w) * fcv[7];
    float sh0 = lo16(B.x), sx = hi16(B.x), sy = lo16(B.y), sz = hi16(B.y);
    uint2 q = *(const uint2*)(hlane + B.z);  // {hs, hv0, hv1, hv2} @ u
    float ga = lo16(q.x);
    float g1 = lo ? ga : hi16(q.x);
    float g2 = lo ? ga : lo16(q.y);
    float g3 = lo ? ga : hi16(q.y);
    float c1 = lo ? sh0 : sx;
    float c2 = lo ? 0.f : sy;
    float c3 = lo ? 0.f : sz;
    acc_s += ws_ * (g1 * c1 + g2 * c2 + g3 * c3);
    float tw = wv_ * sh0;
    float t0 = lo ? wv_ * sx : tw;
    float t1 = lo ? wv_ * sy : tw;
    float t2 = lo ? wv_ * sz : tw;
    av0 += g1 * t0; av1 += g2 * t1; av2 += g3 * t2;
}

__global__ __launch_bounds__(256) void k2b_gather(
    const u32* __restrict__ edata, const float* __restrict__ fc2,
    const u16* __restrict__ hsv, const int* __restrict__ row_ptr,
    const float* __restrict__ W2s, const float* __restrict__ W2v,
    float* __restrict__ out)
{
    __shared__ float sred[4][256];
    const int tid = threadIdx.x;
    const int wv = tid >> 6, lane = tid & 63;
    const int n = blockIdx.x * 4 + wv;
    const int beg = __builtin_amdgcn_readfirstlane(row_ptr[n]);
    const int end = __builtin_amdgcn_readfirstlane(row_ptr[n + 1]);

    const float inv3 = 0.5773502691896258f;  // 1/sqrt(3)
    const int u = lane & 31;
    const bool lo = lane < 32;
    const int cs = lo ? lane : (96 + u);
    const int cv = lo ? (32 + u) : (64 + u);
    float fcs[8], fcv[8];
#pragma unroll
    for (int j = 0; j < 8; j++) {
        float sscale = lo ? 1.f : inv3;
        fcs[j] = fc2[j * 128 + cs] * sscale;
        fcv[j] = fc2[j * 128 + cv];
    }
    const char* hlane = (const char*)hsv + u * 8;  // + B.z per edge

    float as[4] = {0.f, 0.f, 0.f, 0.f};
    float a0[4] = {0.f, 0.f, 0.f, 0.f};
    float a1[4] = {0.f, 0.f, 0.f, 0.f};
    float a2[4] = {0.f, 0.f, 0.f, 0.f};
    int s = beg;
    for (; s + 3 < end; s += 4) {
        edge_body(edata + (size_t)(s + 0) * 8, hlane, fcs, fcv, lo, as[0], a0[0], a1[0], a2[0]);
        edge_body(edata + (size_t)(s + 1) * 8, hlane, fcs, fcv, lo, as[1], a0[1], a1[1], a2[1]);
        edge_body(edata + (size_t)(s + 2) * 8, hlane, fcs, fcv, lo, as[2], a0[2], a1[2], a2[2]);
        edge_body(edata + (size_t)(s + 3) * 8, hlane, fcs, fcv, lo, as[3], a0[3], a1[3], a2[3]);
    }
    for (; s < end; s++)
        edge_body(edata + (size_t)s * 8, hlane, fcs, fcv, lo, as[0], a0[0], a1[0], a2[0]);
    float acc_s = (as[0] + as[1]) + (as[2] + as[3]);
    float av0 = (a0[0] + a0[1]) + (a0[2] + a0[3]);
    float av1 = (a1[0] + a1[1]) + (a1[2] + a1[3]);
    float av2 = (a2[0] + a2[1]) + (a2[2] + a2[3]);

    // per-wave-private LDS transpose (same wave writes & reads -> no barrier)
    float* red = sred[wv];
    red[lane] = acc_s;               // red[c]        = agg_s[c]
    red[64 + lane * 3 + 0] = av0;    // red[64+3c+m]  = agg_v[c][m]
    red[64 + lane * 3 + 1] = av1;
    red[64 + lane * 3 + 2] = av2;

    // branch-free epilogue: each lane -> 2 dot-64 products
    const float sc2 = 0.03125f;  // inv_n * inv2
    const int w = lane & 31;
    const int b0 = lo ? 0 : 64;
    const int s0 = lo ? 1 : 3;
    const int b1 = lo ? 66 : 65;
    const float* __restrict__ Wp0 = lo ? W2s : W2v;
    float p0 = 0.f, p1 = 0.f;
#pragma unroll 8
    for (int c = 0; c < 64; c++) {
        float r0 = red[b0 + c * s0];
        float r1 = red[b1 + c * 3];
        p0 += r0 * Wp0[c * 32 + w];
        p1 += r1 * W2v[c * 32 + w];
    }
    const size_t o = (size_t)n * 128;
    const int addr0 = lo ? w : (32 + 3 * w);
    const int addr1 = lo ? (32 + 3 * w + 2) : (32 + 3 * w + 1);
    out[o + addr0] += p0 * sc2;
    out[o + addr1] += p1 * sc2;
}

extern "C" void kernel_launch(void* const* d_in, const int* in_sizes, int n_in,
                              void* d_out, int out_size, void* d_ws, size_t ws_size,
                              hipStream_t stream) {
    const float* x    = (const float*)d_in[0];
    const float* h    = (const float*)d_in[1];
    const float* emb  = (const float*)d_in[2];
    const float* esh  = (const float*)d_in[3];
    const int*   eidx = (const int*)d_in[4];
    const float* W1s  = (const float*)d_in[5];
    const float* W1v  = (const float*)d_in[6];
    const float* fc1  = (const float*)d_in[7];
    const float* fc2  = (const float*)d_in[8];
    const float* Wscs = (const float*)d_in[9];
    const float* Wscv = (const float*)d_in[10];
    const float* W2s  = (const float*)d_in[11];
    const float* W2v  = (const float*)d_in[12];
    float* out = (float*)d_out;

    // ws: deg[NN] | row_ptr[NN+1] | cursor[NN] | bsum[196] | pad |
    //     edata u32[EE*8] (25.6MB) | hsv u16[NN*128] (12.8MB) | wscsT/wscvT/w1sT/w1vT
    int* deg      = (int*)d_ws;
    int* row_ptr  = deg + NN;
    int* cursor   = row_ptr + (NN + 1);
    int* bsum     = (int*)d_ws + 150004;
    u32* edata    = (u32*)d_ws + 150208;  // 16B-aligned
    u16* hsv      = (u16*)(edata + (size_t)EE * 8);
    u16* wscsT    = hsv + (size_t)NN * 128;
    u16* wscvT    = wscsT + 16384;
    u16* w1sT     = wscvT + 16384;
    u16* w1vT     = w1sT + 1024;

    hipMemsetAsync(d_ws, 0, (size_t)(3 * NN + 1) * 4, stream);
    k_prep<<<3189, 256, 0, stream>>>(eidx, deg, Wscs, Wscv, W1s, W1v, wscsT, wscvT, w1sT, w1vT);
    k_scan1<<<SCAN_B, 256, 0, stream>>>(deg, bsum);
    k_scan2<<<SCAN_B, 256, 0, stream>>>(deg, bsum, row_ptr);
    k2a1<<<3125 + 391, 256, 0, stream>>>(emb, esh, eidx, fc1, row_ptr, cursor, edata,
                                         x, h, wscsT, wscvT, w1sT, w1vT, hsv, out);
    k2b_gather<<<NN / 4, 256, 0, stream>>>(edata, fc2, hsv, row_ptr, W2s, W2v, out);
}

// Round 17
// 230.087 us; speedup vs baseline: 1.1949x; 1.1949x over previous
//
#include <hip/hip_runtime.h>
#include <hip/hip_bf16.h>

#define NN 50000
#define EE 800000
#define SCAN_B 196  // 196*256 = 50176 >= NN+1

typedef unsigned short u16;
typedef unsigned int u32;
typedef float f32x16 __attribute__((ext_vector_type(16)));
typedef short bf16x8_t __attribute__((ext_vector_type(8)));

__device__ __forceinline__ float bfu2f(u16 b) { return __builtin_bit_cast(float, ((u32)b) << 16); }
__device__ __forceinline__ float lo16(u32 d) { return __builtin_bit_cast(float, d << 16); }
__device__ __forceinline__ float hi16(u32 d) { return __builtin_bit_cast(float, d & 0xffff0000u); }
__device__ __forceinline__ u16 f2bfu(float f) {
    u32 u = __builtin_bit_cast(u32, f);
    u32 r = (u + 0x7fffu + ((u >> 16) & 1u)) >> 16;
    return (u16)r;
}
__device__ __forceinline__ u32 cvt_pk_bf16(float lo, float hi) {
    u32 r;
    asm("v_cvt_pk_bf16_f32 %0, %1, %2" : "=v"(r) : "v"(lo), "v"(hi));
    return r;
}

// ---------------------------------------------------------------------------
// k_prep: fused {histogram over dst} + {weight transpose for MFMA}.
// blocks [0,3125): hist (3125*256 == EE exactly). blocks [3125,3189): wprep.
// ---------------------------------------------------------------------------
__global__ __launch_bounds__(256) void k_prep(
    const int* __restrict__ eidx, int* __restrict__ deg,
    const float* __restrict__ Wscs, const float* __restrict__ Wscv,
    const float* __restrict__ W1s, const float* __restrict__ W1v,
    u16* __restrict__ wscsT, u16* __restrict__ wscvT,
    u16* __restrict__ w1sT, u16* __restrict__ w1vT)
{
    const int b = blockIdx.x;
    if (b < 3125) {
        int e = b * 256 + threadIdx.x;
        atomicAdd(&deg[eidx[e]], 1);
    } else {
        int i = (b - 3125) * 256 + threadIdx.x;
        if (i < 16384) {
            int u = i >> 9, v = (i >> 5) & 15, w = i & 31;
            wscsT[(u * 32 + w) * 16 + v] = f2bfu(Wscs[i]);
            wscvT[(u * 32 + w) * 16 + v] = f2bfu(Wscv[i]);
        }
        if (i < 1024) {
            int u = i >> 5, w = i & 31;
            w1sT[w * 32 + u] = f2bfu(W1s[i]);
            w1vT[w * 32 + u] = f2bfu(W1v[i]);
        }
    }
}

// ---------------------------------------------------------------------------
// two-phase parallel scan
// ---------------------------------------------------------------------------
__global__ __launch_bounds__(256) void k_scan1(const int* __restrict__ deg, int* __restrict__ bsum) {
    __shared__ int red[256];
    const int tid = threadIdx.x;
    int i = blockIdx.x * 256 + tid;
    int v = (i < NN) ? deg[i] : 0;
    red[tid] = v;
    __syncthreads();
    for (int off = 128; off > 0; off >>= 1) {
        if (tid < off) red[tid] += red[tid + off];
        __syncthreads();
    }
    if (tid == 0) bsum[blockIdx.x] = red[0];
}

__global__ __launch_bounds__(256) void k_scan2(
    const int* __restrict__ deg, const int* __restrict__ bsum, int* __restrict__ row_ptr)
{
    const int b = blockIdx.x;
    const int tid = threadIdx.x;
    __shared__ int pre[256];
    __shared__ int bpre;
    int pv = (tid < b) ? bsum[tid] : 0;  // b <= 195 < 256
    pre[tid] = pv;
    __syncthreads();
    for (int off = 128; off > 0; off >>= 1) {
        if (tid < off) pre[tid] += pre[tid + off];
        __syncthreads();
    }
    if (tid == 0) bpre = pre[0];
    __syncthreads();
    int i = b * 256 + tid;
    int v = (i < NN) ? deg[i] : 0;
    pre[tid] = v;
    __syncthreads();
    for (int off = 1; off < 256; off <<= 1) {
        int t = (tid >= off) ? pre[tid - off] : 0;
        __syncthreads();
        pre[tid] += t;
        __syncthreads();
    }
    int excl = pre[tid] - v;
    if (i <= NN) row_ptr[i] = bpre + excl;  // i==NN -> EE
}

// ---------------------------------------------------------------------------
// k1 tile body: one wave per 32-node tile. hsv m-major (round-15 verified):
// row = [32 hs][m=0: 32][m=1: 32][m=2: 32].
// ---------------------------------------------------------------------------
__device__ __forceinline__ void k1_tile(
    int base, int l, u16* __restrict__ sh,
    const float* __restrict__ x, const float* __restrict__ h,
    const u16* __restrict__ wscsT, const u16* __restrict__ wscvT,
    const u16* __restrict__ w1sT, const u16* __restrict__ w1vT,
    u16* __restrict__ hsv, float* __restrict__ out)
{
    u32* sh32 = (u32*)sh;
    const int n = l & 31;
    const int hi = l >> 5;

    {
        int r = base + (l >> 1);
        if (r >= NN) r = NN - 1;
        const float* hp = h + (size_t)r * 128 + (l & 1) * 64;
        int nn = l >> 1;
        int cp0 = (l & 1) * 32;
#pragma unroll
        for (int q = 0; q < 16; q++) {
            float4 f = *(const float4*)(hp + q * 4);
            sh32[(cp0 + 2 * q + 0) * 32 + nn] = cvt_pk_bf16(f.x, f.y);
            sh32[(cp0 + 2 * q + 1) * 32 + nn] = cvt_pk_bf16(f.z, f.w);
        }
    }
    float xv0, xv1, xv2, xv3, xv4, xv5, xv6, xv7;
    {
        int r = base + n;
        if (r >= NN) r = NN - 1;
        const float* xp = x + (size_t)r * 16 + hi * 8;
        float4 a = *(const float4*)xp;
        float4 b = *(const float4*)(xp + 4);
        xv0 = a.x; xv1 = a.y; xv2 = a.z; xv3 = a.w;
        xv4 = b.x; xv5 = b.y; xv6 = b.z; xv7 = b.w;
    }
    __syncthreads();

    f32x16 accS, accX, accY, accZ;
#pragma unroll
    for (int i = 0; i < 16; i++) { accS[i] = 0.f; accX[i] = 0.f; accY[i] = 0.f; accZ[i] = 0.f; }

#define MK_A(A, s)                                                     \
    { union { u32 w[4]; bf16x8_t v; } t_;                              \
      t_.w[0] = cvt_pk_bf16((s) * xv0, (s) * xv1);                     \
      t_.w[1] = cvt_pk_bf16((s) * xv2, (s) * xv3);                     \
      t_.w[2] = cvt_pk_bf16((s) * xv4, (s) * xv5);                     \
      t_.w[3] = cvt_pk_bf16((s) * xv6, (s) * xv7);                     \
      A = t_.v; }

    const size_t boff = (size_t)n * 16 + hi * 8;
    bf16x8_t Bs = *(const bf16x8_t*)(wscsT + boff);
    bf16x8_t Bv = *(const bf16x8_t*)(wscvT + boff);
#pragma unroll 2
    for (int u = 0; u < 32; u++) {
        bf16x8_t BsN, BvN;
        if (u < 31) {
            BsN = *(const bf16x8_t*)(wscsT + (size_t)(u + 1) * 512 + boff);
            BvN = *(const bf16x8_t*)(wscvT + (size_t)(u + 1) * 512 + boff);
        }
        float hsu = bfu2f(sh[(u >> 1) * 64 + n * 2 + (u & 1)]);
        int c = 32 + 3 * u;
        float hx = bfu2f(sh[(c >> 1) * 64 + n * 2 + (c & 1)]);
        float hy = bfu2f(sh[((c + 1) >> 1) * 64 + n * 2 + ((c + 1) & 1)]);
        float hz = bfu2f(sh[((c + 2) >> 1) * 64 + n * 2 + ((c + 2) & 1)]);
        bf16x8_t A;
        MK_A(A, hsu); accS = __builtin_amdgcn_mfma_f32_32x32x16_bf16(A, Bs, accS, 0, 0, 0);
        MK_A(A, hx);  accX = __builtin_amdgcn_mfma_f32_32x32x16_bf16(A, Bv, accX, 0, 0, 0);
        MK_A(A, hy);  accY = __builtin_amdgcn_mfma_f32_32x32x16_bf16(A, Bv, accY, 0, 0, 0);
        MK_A(A, hz);  accZ = __builtin_amdgcn_mfma_f32_32x32x16_bf16(A, Bv, accZ, 0, 0, 0);
        Bs = BsN; Bv = BvN;
    }
#undef MK_A

    const float inv_sc = 0.04419417382415922f;  // 1/sqrt(512)
#pragma unroll
    for (int r = 0; r < 16; r++) {
        int node2 = base + ((r & 3) + 8 * (r >> 2) + 4 * hi);
        if (node2 < NN) {
            float* op = out + (size_t)node2 * 128;
            op[n] = accS[r] * inv_sc;
            op[32 + n * 3 + 0] = accX[r] * inv_sc;
            op[32 + n * 3 + 1] = accY[r] * inv_sc;
            op[32 + n * 3 + 2] = accZ[r] * inv_sc;
        }
    }

    const float inv_m = 0.17677669529663687f;  // 1/sqrt(32)
    {
        f32x16 aw;
#pragma unroll
        for (int i = 0; i < 16; i++) aw[i] = 0.f;
#pragma unroll
        for (int k0 = 0; k0 < 2; k0++) {
            union { u32 w[4]; bf16x8_t v; } A;
#pragma unroll
            for (int q = 0; q < 4; q++)
                A.w[q] = sh32[(8 * k0 + 4 * hi + q) * 32 + n];
            bf16x8_t B = *(const bf16x8_t*)(w1sT + n * 32 + 16 * k0 + 8 * hi);
            aw = __builtin_amdgcn_mfma_f32_32x32x16_bf16(A.v, B, aw, 0, 0, 0);
        }
#pragma unroll
        for (int r = 0; r < 16; r++) {
            int node2 = base + ((r & 3) + 8 * (r >> 2) + 4 * hi);
            if (node2 < NN) hsv[(size_t)node2 * 128 + n] = f2bfu(aw[r] * inv_m);
        }
    }
#pragma unroll
    for (int m = 0; m < 3; m++) {
        f32x16 aw;
#pragma unroll
        for (int i = 0; i < 16; i++) aw[i] = 0.f;
#pragma unroll
        for (int k0 = 0; k0 < 2; k0++) {
            union { u32 w[4]; bf16x8_t v; } A;
#pragma unroll
            for (int j = 0; j < 8; j += 2) {
                int u0 = 16 * k0 + 8 * hi + j;
                int c0 = 32 + 3 * u0 + m, c1 = c0 + 3;
                u16 a = sh[(c0 >> 1) * 64 + n * 2 + (c0 & 1)];
                u16 b = sh[(c1 >> 1) * 64 + n * 2 + (c1 & 1)];
                A.w[j >> 1] = (u32)a | ((u32)b << 16);
            }
            bf16x8_t B = *(const bf16x8_t*)(w1vT + n * 32 + 16 * k0 + 8 * hi);
            aw = __builtin_amdgcn_mfma_f32_32x32x16_bf16(A.v, B, aw, 0, 0, 0);
        }
#pragma unroll
        for (int r = 0; r < 16; r++) {
            int node2 = base + ((r & 3) + 8 * (r >> 2) + 4 * hi);
            if (node2 < NN) hsv[(size_t)node2 * 128 + 32 + m * 32 + n] = f2bfu(aw[r] * inv_m);
        }
    }
}

// ---------------------------------------------------------------------------
// k2a1: fused {k2a edge MLP + CSR scatter} (blocks [0,3125)) and
//       {k1 MFMA node prep} (blocks [3125,3516): 4 waves x 4 tiles each).
// ---------------------------------------------------------------------------
__global__ __launch_bounds__(256) void k2a1(
    const float* __restrict__ emb, const float* __restrict__ esh,
    const int* __restrict__ eidx, const float* __restrict__ fc1,
    const int* __restrict__ row_ptr, int* __restrict__ cursor,
    u32* __restrict__ edata,
    const float* __restrict__ x, const float* __restrict__ h,
    const u16* __restrict__ wscsT, const u16* __restrict__ wscvT,
    const u16* __restrict__ w1sT, const u16* __restrict__ w1vT,
    u16* __restrict__ hsv, float* __restrict__ out)
{
    __shared__ float sfc1[64];
    __shared__ __align__(16) u16 shh[4][4096];  // 8KB per wave (32KB)
    const int b = blockIdx.x;
    const int tid = threadIdx.x;
    if (b < 3125) {
        if (tid < 64) sfc1[tid] = fc1[tid];
        __syncthreads();
        int e = b * 256 + tid;  // 3125*256 == EE
        const float invb = 0.3535533905932738f;  // 1/sqrt(8)
        float4 ea = *(const float4*)(emb + (size_t)e * 8);
        float4 eb = *(const float4*)(emb + (size_t)e * 8 + 4);
        float em[8] = {ea.x, ea.y, ea.z, ea.w, eb.x, eb.y, eb.z, eb.w};
        float z[8];
#pragma unroll
        for (int k = 0; k < 8; k++) {
            float t = 0.f;
#pragma unroll
            for (int j = 0; j < 8; j++) t += em[j] * sfc1[j * 8 + k];
            t *= invb;
            z[k] = (t / (1.f + __expf(-t))) * invb;  // fold 1/sqrt(HID)
        }
        float4 sh = *(const float4*)(esh + (size_t)e * 4);
        int dst = eidx[e], src = eidx[EE + e];
        int p = atomicAdd(&cursor[dst], 1);
        size_t slot = (size_t)row_ptr[dst] + p;
        u32* wp = edata + slot * 8;
        uint4 A, B;
        A.x = cvt_pk_bf16(z[0], z[1]);
        A.y = cvt_pk_bf16(z[2], z[3]);
        A.z = cvt_pk_bf16(z[4], z[5]);
        A.w = cvt_pk_bf16(z[6], z[7]);
        B.x = cvt_pk_bf16(sh.x, sh.y);
        B.y = cvt_pk_bf16(sh.z, sh.w);
        B.z = ((u32)src) << 8;  // byte offset of hsv row (128 u16 = 256 B)
        B.w = 0;
        *(uint4*)wp = A;
        *(uint4*)(wp + 4) = B;
    } else {
        const int wv = tid >> 6, l = tid & 63;
        int tile = (b - 3125) * 4 + wv;  // up to 1563; tile 1563 fully clamped
        k1_tile(tile * 32, l, shh[wv], x, h, wscsT, wscvT, w1sT, w1vT, hsv, out);
    }
}

// ---------------------------------------------------------------------------
// K2b: gather + aggregate + fused output transform (round-15 verified exact:
// 3 scalar gathers, m-major hsv, branch-free epilogue, no barrier).
// ---------------------------------------------------------------------------
__device__ __forceinline__ void edge_body(
    const u32* __restrict__ r, const char* __restrict__ hbase,
    const float* fcs, const float* fcv, bool lo, int o1, int o2, int o3,
    float& acc_s, float& av0, float& av1, float& av2)
{
    uint4 A = *(const uint4*)r;
    uint4 B = *(const uint4*)(r + 4);
    float ws_ = lo16(A.x) * fcs[0] + hi16(A.x) * fcs[1] + lo16(A.y) * fcs[2] + hi16(A.y) * fcs[3]
              + lo16(A.z) * fcs[4] + hi16(A.z) * fcs[5] + lo16(A.w) * fcs[6] + hi16(A.w) * fcs[7];
    float wv_ = lo16(A.x) * fcv[0] + hi16(A.x) * fcv[1] + lo16(A.y) * fcv[2] + hi16(A.y) * fcv[3]
              + lo16(A.z) * fcv[4] + hi16(A.z) * fcv[5] + lo16(A.w) * fcv[6] + hi16(A.w) * fcv[7];
    float sh0 = lo16(B.x), sx = hi16(B.x), sy = lo16(B.y), sz = hi16(B.y);
    const u16* hp = (const u16*)(hbase + B.z);  // B.z = src*256 bytes
    float g1 = bfu2f(hp[o1]), g2 = bfu2f(hp[o2]), g3 = bfu2f(hp[o3]);
    float c1 = lo ? sh0 : sx;
    float c2 = lo ? 0.f : sy;
    float c3 = lo ? 0.f : sz;
    acc_s += ws_ * (g1 * c1 + g2 * c2 + g3 * c3);
    float tw = wv_ * sh0;
    float t0 = lo ? wv_ * sx : tw;
    float t1 = lo ? wv_ * sy : tw;
    float t2 = lo ? wv_ * sz : tw;
    av0 += g1 * t0; av1 += g2 * t1; av2 += g3 * t2;
}

__global__ __launch_bounds__(256) void k2b_gather(
    const u32* __restrict__ edata, const float* __restrict__ fc2,
    const u16* __restrict__ hsv, const int* __restrict__ row_ptr,
    const float* __restrict__ W2s, const float* __restrict__ W2v,
    float* __restrict__ out)
{
    __shared__ float sred[4][256];
    const int tid = threadIdx.x;
    const int wv = tid >> 6, lane = tid & 63;
    const int n = blockIdx.x * 4 + wv;
    const int beg = __builtin_amdgcn_readfirstlane(row_ptr[n]);
    const int end = __builtin_amdgcn_readfirstlane(row_ptr[n + 1]);

    const float inv3 = 0.5773502691896258f;  // 1/sqrt(3)
    const int u = lane & 31;
    const bool lo = lane < 32;
    const int cs = lo ? lane : (96 + u);
    const int cv = lo ? (32 + u) : (64 + u);
    const int o1 = lo ? u : (32 + u);
    const int o2 = lo ? u : (64 + u);
    const int o3 = lo ? u : (96 + u);
    float fcs[8], fcv[8];
#pragma unroll
    for (int j = 0; j < 8; j++) {
        float sscale = lo ? 1.f : inv3;
        fcs[j] = fc2[j * 128 + cs] * sscale;
        fcv[j] = fc2[j * 128 + cv];
    }
    const char* hbase = (const char*)hsv;

    float as[4] = {0.f, 0.f, 0.f, 0.f};
    float a0[4] = {0.f, 0.f, 0.f, 0.f};
    float a1[4] = {0.f, 0.f, 0.f, 0.f};
    float a2[4] = {0.f, 0.f, 0.f, 0.f};
    int s = beg;
    for (; s + 3 < end; s += 4) {
        edge_body(edata + (size_t)(s + 0) * 8, hbase, fcs, fcv, lo, o1, o2, o3, as[0], a0[0], a1[0], a2[0]);
        edge_body(edata + (size_t)(s + 1) * 8, hbase, fcs, fcv, lo, o1, o2, o3, as[1], a0[1], a1[1], a2[1]);
        edge_body(edata + (size_t)(s + 2) * 8, hbase, fcs, fcv, lo, o1, o2, o3, as[2], a0[2], a1[2], a2[2]);
        edge_body(edata + (size_t)(s + 3) * 8, hbase, fcs, fcv, lo, o1, o2, o3, as[3], a0[3], a1[3], a2[3]);
    }
    for (; s < end; s++)
        edge_body(edata + (size_t)s * 8, hbase, fcs, fcv, lo, o1, o2, o3, as[0], a0[0], a1[0], a2[0]);
    float acc_s = (as[0] + as[1]) + (as[2] + as[3]);
    float av0 = (a0[0] + a0[1]) + (a0[2] + a0[3]);
    float av1 = (a1[0] + a1[1]) + (a1[2] + a1[3]);
    float av2 = (a2[0] + a2[1]) + (a2[2] + a2[3]);

    // per-wave-private LDS transpose (same wave writes & reads -> no barrier)
    float* red = sred[wv];
    red[lane] = acc_s;               // red[c]        = agg_s[c]
    red[64 + lane * 3 + 0] = av0;    // red[64+3c+m]  = agg_v[c][m]
    red[64 + lane * 3 + 1] = av1;
    red[64 + lane * 3 + 2] = av2;

    // branch-free epilogue: each lane -> 2 dot-64 products
    const float sc2 = 0.03125f;  // inv_n * inv2
    const int w = lane & 31;
    const int b0 = lo ? 0 : 64;
    const int s0 = lo ? 1 : 3;
    const int b1 = lo ? 66 : 65;
    const float* __restrict__ Wp0 = lo ? W2s : W2v;
    float p0 = 0.f, p1 = 0.f;
#pragma unroll 8
    for (int c = 0; c < 64; c++) {
        float r0 = red[b0 + c * s0];
        float r1 = red[b1 + c * 3];
        p0 += r0 * Wp0[c * 32 + w];
        p1 += r1 * W2v[c * 32 + w];
    }
    const size_t o = (size_t)n * 128;
    const int addr0 = lo ? w : (32 + 3 * w);
    const int addr1 = lo ? (32 + 3 * w + 2) : (32 + 3 * w + 1);
    out[o + addr0] += p0 * sc2;
    out[o + addr1] += p1 * sc2;
}

extern "C" void kernel_launch(void* const* d_in, const int* in_sizes, int n_in,
                              void* d_out, int out_size, void* d_ws, size_t ws_size,
                              hipStream_t stream) {
    const float* x    = (const float*)d_in[0];
    const float* h    = (const float*)d_in[1];
    const float* emb  = (const float*)d_in[2];
    const float* esh  = (const float*)d_in[3];
    const int*   eidx = (const int*)d_in[4];
    const float* W1s  = (const float*)d_in[5];
    const float* W1v  = (const float*)d_in[6];
    const float* fc1  = (const float*)d_in[7];
    const float* fc2  = (const float*)d_in[8];
    const float* Wscs = (const float*)d_in[9];
    const float* Wscv = (const float*)d_in[10];
    const float* W2s  = (const float*)d_in[11];
    const float* W2v  = (const float*)d_in[12];
    float* out = (float*)d_out;

    // ws: deg[NN] | row_ptr[NN+1] | cursor[NN] | bsum[196] | pad |
    //     edata u32[EE*8] (25.6MB) | hsv u16[NN*128] (12.8MB) | wscsT/wscvT/w1sT/w1vT
    int* deg      = (int*)d_ws;
    int* row_ptr  = deg + NN;
    int* cursor   = row_ptr + (NN + 1);
    int* bsum     = (int*)d_ws + 150004;
    u32* edata    = (u32*)d_ws + 150208;  // 16B-aligned
    u16* hsv      = (u16*)(edata + (size_t)EE * 8);
    u16* wscsT    = hsv + (size_t)NN * 128;
    u16* wscvT    = wscsT + 16384;
    u16* w1sT     = wscvT + 16384;
    u16* w1vT     = w1sT + 1024;

    hipMemsetAsync(d_ws, 0, (size_t)(3 * NN + 1) * 4, stream);
    k_prep<<<3189, 256, 0, stream>>>(eidx, deg, Wscs, Wscv, W1s, W1v, wscsT, wscvT, w1sT, w1vT);
    k_scan1<<<SCAN_B, 256, 0, stream>>>(deg, bsum);
    k_scan2<<<SCAN_B, 256, 0, stream>>>(deg, bsum, row_ptr);
    k2a1<<<3125 + 391, 256, 0, stream>>>(emb, esh, eidx, fc1, row_ptr, cursor, edata,
                                         x, h, wscsT, wscvT, w1sT, w1vT, hsv, out);
    k2b_gather<<<NN / 4, 256, 0, stream>>>(edata, fc2, hsv, row_ptr, W2s, W2v, out);
}

// Round 19
// 224.063 us; speedup vs baseline: 1.2270x; 1.0269x over previous
//
#include <hip/hip_runtime.h>
#include <hip/hip_bf16.h>

#define NN 50000
#define EE 800000
#define SCAN_B 196  // 196*256 = 50176 >= NN+1

typedef unsigned short u16;
typedef unsigned int u32;
typedef float f32x16 __attribute__((ext_vector_type(16)));
typedef short bf16x8_t __attribute__((ext_vector_type(8)));
typedef const __attribute__((address_space(4))) u32 cu32;  // constant/scalar loads

__device__ __forceinline__ float bfu2f(u16 b) { return __builtin_bit_cast(float, ((u32)b) << 16); }
__device__ __forceinline__ float lo16(u32 d) { return __builtin_bit_cast(float, d << 16); }
__device__ __forceinline__ float hi16(u32 d) { return __builtin_bit_cast(float, d & 0xffff0000u); }
__device__ __forceinline__ u16 f2bfu(float f) {
    u32 u = __builtin_bit_cast(u32, f);
    u32 r = (u + 0x7fffu + ((u >> 16) & 1u)) >> 16;
    return (u16)r;
}
__device__ __forceinline__ u32 cvt_pk_bf16(float lo, float hi) {
    u32 r;
    asm("v_cvt_pk_bf16_f32 %0, %1, %2" : "=v"(r) : "v"(lo), "v"(hi));
    return r;
}

// ---------------------------------------------------------------------------
// k_prep: fused {histogram over dst} + {weight transpose for MFMA}.
// ---------------------------------------------------------------------------
__global__ __launch_bounds__(256) void k_prep(
    const int* __restrict__ eidx, int* __restrict__ deg,
    const float* __restrict__ Wscs, const float* __restrict__ Wscv,
    const float* __restrict__ W1s, const float* __restrict__ W1v,
    u16* __restrict__ wscsT, u16* __restrict__ wscvT,
    u16* __restrict__ w1sT, u16* __restrict__ w1vT)
{
    const int b = blockIdx.x;
    if (b < 3125) {
        int e = b * 256 + threadIdx.x;
        atomicAdd(&deg[eidx[e]], 1);
    } else {
        int i = (b - 3125) * 256 + threadIdx.x;
        if (i < 16384) {
            int u = i >> 9, v = (i >> 5) & 15, w = i & 31;
            wscsT[(u * 32 + w) * 16 + v] = f2bfu(Wscs[i]);
            wscvT[(u * 32 + w) * 16 + v] = f2bfu(Wscv[i]);
        }
        if (i < 1024) {
            int u = i >> 5, w = i & 31;
            w1sT[w * 32 + u] = f2bfu(W1s[i]);
            w1vT[w * 32 + u] = f2bfu(W1v[i]);
        }
    }
}

// ---------------------------------------------------------------------------
// two-phase parallel scan
// ---------------------------------------------------------------------------
__global__ __launch_bounds__(256) void k_scan1(const int* __restrict__ deg, int* __restrict__ bsum) {
    __shared__ int red[256];
    const int tid = threadIdx.x;
    int i = blockIdx.x * 256 + tid;
    int v = (i < NN) ? deg[i] : 0;
    red[tid] = v;
    __syncthreads();
    for (int off = 128; off > 0; off >>= 1) {
        if (tid < off) red[tid] += red[tid + off];
        __syncthreads();
    }
    if (tid == 0) bsum[blockIdx.x] = red[0];
}

__global__ __launch_bounds__(256) void k_scan2(
    const int* __restrict__ deg, const int* __restrict__ bsum, int* __restrict__ row_ptr)
{
    const int b = blockIdx.x;
    const int tid = threadIdx.x;
    __shared__ int pre[256];
    __shared__ int bpre;
    int pv = (tid < b) ? bsum[tid] : 0;  // b <= 195 < 256
    pre[tid] = pv;
    __syncthreads();
    for (int off = 128; off > 0; off >>= 1) {
        if (tid < off) pre[tid] += pre[tid + off];
        __syncthreads();
    }
    if (tid == 0) bpre = pre[0];
    __syncthreads();
    int i = b * 256 + tid;
    int v = (i < NN) ? deg[i] : 0;
    pre[tid] = v;
    __syncthreads();
    for (int off = 1; off < 256; off <<= 1) {
        int t = (tid >= off) ? pre[tid - off] : 0;
        __syncthreads();
        pre[tid] += t;
        __syncthreads();
    }
    int excl = pre[tid] - v;
    if (i <= NN) row_ptr[i] = bpre + excl;  // i==NN -> EE
}

// ---------------------------------------------------------------------------
// k1 tile body: one wave per 32-node tile. hsv m-major (verified):
// row = [32 hs][m=0: 32][m=1: 32][m=2: 32].
// ---------------------------------------------------------------------------
__device__ __forceinline__ void k1_tile(
    int base, int l, u16* __restrict__ sh,
    const float* __restrict__ x, const float* __restrict__ h,
    const u16* __restrict__ wscsT, const u16* __restrict__ wscvT,
    const u16* __restrict__ w1sT, const u16* __restrict__ w1vT,
    u16* __restrict__ hsv, float* __restrict__ out)
{
    u32* sh32 = (u32*)sh;
    const int n = l & 31;
    const int hi = l >> 5;

    {
        int r = base + (l >> 1);
        if (r >= NN) r = NN - 1;
        const float* hp = h + (size_t)r * 128 + (l & 1) * 64;
        int nn = l >> 1;
        int cp0 = (l & 1) * 32;
#pragma unroll
        for (int q = 0; q < 16; q++) {
            float4 f = *(const float4*)(hp + q * 4);
            sh32[(cp0 + 2 * q + 0) * 32 + nn] = cvt_pk_bf16(f.x, f.y);
            sh32[(cp0 + 2 * q + 1) * 32 + nn] = cvt_pk_bf16(f.z, f.w);
        }
    }
    float xv0, xv1, xv2, xv3, xv4, xv5, xv6, xv7;
    {
        int r = base + n;
        if (r >= NN) r = NN - 1;
        const float* xp = x + (size_t)r * 16 + hi * 8;
        float4 a = *(const float4*)xp;
        float4 b = *(const float4*)(xp + 4);
        xv0 = a.x; xv1 = a.y; xv2 = a.z; xv3 = a.w;
        xv4 = b.x; xv5 = b.y; xv6 = b.z; xv7 = b.w;
    }
    __syncthreads();

    f32x16 accS, accX, accY, accZ;
#pragma unroll
    for (int i = 0; i < 16; i++) { accS[i] = 0.f; accX[i] = 0.f; accY[i] = 0.f; accZ[i] = 0.f; }

#define MK_A(A, s)                                                     \
    { union { u32 w[4]; bf16x8_t v; } t_;                              \
      t_.w[0] = cvt_pk_bf16((s) * xv0, (s) * xv1);                     \
      t_.w[1] = cvt_pk_bf16((s) * xv2, (s) * xv3);                     \
      t_.w[2] = cvt_pk_bf16((s) * xv4, (s) * xv5);                     \
      t_.w[3] = cvt_pk_bf16((s) * xv6, (s) * xv7);                     \
      A = t_.v; }

    const size_t boff = (size_t)n * 16 + hi * 8;
    bf16x8_t Bs = *(const bf16x8_t*)(wscsT + boff);
    bf16x8_t Bv = *(const bf16x8_t*)(wscvT + boff);
#pragma unroll 2
    for (int u = 0; u < 32; u++) {
        bf16x8_t BsN, BvN;
        if (u < 31) {
            BsN = *(const bf16x8_t*)(wscsT + (size_t)(u + 1) * 512 + boff);
            BvN = *(const bf16x8_t*)(wscvT + (size_t)(u + 1) * 512 + boff);
        }
        float hsu = bfu2f(sh[(u >> 1) * 64 + n * 2 + (u & 1)]);
        int c = 32 + 3 * u;
        float hx = bfu2f(sh[(c >> 1) * 64 + n * 2 + (c & 1)]);
        float hy = bfu2f(sh[((c + 1) >> 1) * 64 + n * 2 + ((c + 1) & 1)]);
        float hz = bfu2f(sh[((c + 2) >> 1) * 64 + n * 2 + ((c + 2) & 1)]);
        bf16x8_t A;
        MK_A(A, hsu); accS = __builtin_amdgcn_mfma_f32_32x32x16_bf16(A, Bs, accS, 0, 0, 0);
        MK_A(A, hx);  accX = __builtin_amdgcn_mfma_f32_32x32x16_bf16(A, Bv, accX, 0, 0, 0);
        MK_A(A, hy);  accY = __builtin_amdgcn_mfma_f32_32x32x16_bf16(A, Bv, accY, 0, 0, 0);
        MK_A(A, hz);  accZ = __builtin_amdgcn_mfma_f32_32x32x16_bf16(A, Bv, accZ, 0, 0, 0);
        Bs = BsN; Bv = BvN;
    }
#undef MK_A

    const float inv_sc = 0.04419417382415922f;  // 1/sqrt(512)
#pragma unroll
    for (int r = 0; r < 16; r++) {
        int node2 = base + ((r & 3) + 8 * (r >> 2) + 4 * hi);
        if (node2 < NN) {
            float* op = out + (size_t)node2 * 128;
            op[n] = accS[r] * inv_sc;
            op[32 + n * 3 + 0] = accX[r] * inv_sc;
            op[32 + n * 3 + 1] = accY[r] * inv_sc;
            op[32 + n * 3 + 2] = accZ[r] * inv_sc;
        }
    }

    const float inv_m = 0.17677669529663687f;  // 1/sqrt(32)
    {
        f32x16 aw;
#pragma unroll
        for (int i = 0; i < 16; i++) aw[i] = 0.f;
#pragma unroll
        for (int k0 = 0; k0 < 2; k0++) {
            union { u32 w[4]; bf16x8_t v; } A;
#pragma unroll
            for (int q = 0; q < 4; q++)
                A.w[q] = sh32[(8 * k0 + 4 * hi + q) * 32 + n];
            bf16x8_t B = *(const bf16x8_t*)(w1sT + n * 32 + 16 * k0 + 8 * hi);
            aw = __builtin_amdgcn_mfma_f32_32x32x16_bf16(A.v, B, aw, 0, 0, 0);
        }
#pragma unroll
        for (int r = 0; r < 16; r++) {
            int node2 = base + ((r & 3) + 8 * (r >> 2) + 4 * hi);
            if (node2 < NN) hsv[(size_t)node2 * 128 + n] = f2bfu(aw[r] * inv_m);
        }
    }
#pragma unroll
    for (int m = 0; m < 3; m++) {
        f32x16 aw;
#pragma unroll
        for (int i = 0; i < 16; i++) aw[i] = 0.f;
#pragma unroll
        for (int k0 = 0; k0 < 2; k0++) {
            union { u32 w[4]; bf16x8_t v; } A;
#pragma unroll
            for (int j = 0; j < 8; j += 2) {
                int u0 = 16 * k0 + 8 * hi + j;
                int c0 = 32 + 3 * u0 + m, c1 = c0 + 3;
                u16 a = sh[(c0 >> 1) * 64 + n * 2 + (c0 & 1)];
                u16 b = sh[(c1 >> 1) * 64 + n * 2 + (c1 & 1)];
                A.w[j >> 1] = (u32)a | ((u32)b << 16);
            }
            bf16x8_t B = *(const bf16x8_t*)(w1vT + n * 32 + 16 * k0 + 8 * hi);
            aw = __builtin_amdgcn_mfma_f32_32x32x16_bf16(A.v, B, aw, 0, 0, 0);
        }
#pragma unroll
        for (int r = 0; r < 16; r++) {
            int node2 = base + ((r & 3) + 8 * (r >> 2) + 4 * hi);
            if (node2 < NN) hsv[(size_t)node2 * 128 + 32 + m * 32 + n] = f2bfu(aw[r] * inv_m);
        }
    }
}

// ---------------------------------------------------------------------------
// k2a1: fused {k2a edge MLP + CSR scatter} (blocks [0,3125)) and
//       {k1 MFMA node prep} (blocks [3125,3516): 4 waves x 4 tiles each).
// ---------------------------------------------------------------------------
__global__ __launch_bounds__(256) void k2a1(
    const float* __restrict__ emb, const float* __restrict__ esh,
    const int* __restrict__ eidx, const float* __restrict__ fc1,
    const int* __restrict__ row_ptr, int* __restrict__ cursor,
    u32* __restrict__ edata,
    const float* __restrict__ x, const float* __restrict__ h,
    const u16* __restrict__ wscsT, const u16* __restrict__ wscvT,
    const u16* __restrict__ w1sT, const u16* __restrict__ w1vT,
    u16* __restrict__ hsv, float* __restrict__ out)
{
    __shared__ float sfc1[64];
    __shared__ __align__(16) u16 shh[4][4096];  // 8KB per wave (32KB)
    const int b = blockIdx.x;
    const int tid = threadIdx.x;
    if (b < 3125) {
        if (tid < 64) sfc1[tid] = fc1[tid];
        __syncthreads();
        int e = b * 256 + tid;  // 3125*256 == EE
        const float invb = 0.3535533905932738f;  // 1/sqrt(8)
        float4 ea = *(const float4*)(emb + (size_t)e * 8);
        float4 eb = *(const float4*)(emb + (size_t)e * 8 + 4);
        float em[8] = {ea.x, ea.y, ea.z, ea.w, eb.x, eb.y, eb.z, eb.w};
        float z[8];
#pragma unroll
        for (int k = 0; k < 8; k++) {
            float t = 0.f;
#pragma unroll
            for (int j = 0; j < 8; j++) t += em[j] * sfc1[j * 8 + k];
            t *= invb;
            z[k] = (t / (1.f + __expf(-t))) * invb;  // fold 1/sqrt(HID)
        }
        float4 sh = *(const float4*)(esh + (size_t)e * 4);
        int dst = eidx[e], src = eidx[EE + e];
        int p = atomicAdd(&cursor[dst], 1);
        size_t slot = (size_t)row_ptr[dst] + p;
        u32* wp = edata + slot * 8;
        uint4 A, B;
        A.x = cvt_pk_bf16(z[0], z[1]);
        A.y = cvt_pk_bf16(z[2], z[3]);
        A.z = cvt_pk_bf16(z[4], z[5]);
        A.w = cvt_pk_bf16(z[6], z[7]);
        B.x = cvt_pk_bf16(sh.x, sh.y);
        B.y = cvt_pk_bf16(sh.z, sh.w);
        B.z = ((u32)src) << 8;  // byte offset of hsv row (128 u16 = 256 B)
        B.w = 0;
        *(uint4*)wp = A;
        *(uint4*)(wp + 4) = B;
    } else {
        const int wv = tid >> 6, l = tid & 63;
        int tile = (b - 3125) * 4 + wv;  // up to 1563; tile 1563 fully clamped
        k1_tile(tile * 32, l, shh[wv], x, h, wscsT, wscvT, w1sT, w1vT, hsv, out);
    }
}

// ---------------------------------------------------------------------------
// K2b: gather + aggregate + fused output transform. One wave per dst node.
// Record loaded via addrspace(4) scalar loads (wave-uniform address) ->
// s_load + SALU unpack; weight FMAs read SGPR z; gather base in SGPR.
// ---------------------------------------------------------------------------
__device__ __forceinline__ void edge_body(
    cu32* __restrict__ rec, const char* __restrict__ hbase,
    const float* fcs, const float* fcv, bool lo, int o1, int o2, int o3,
    float& acc_s, float& av0, float& av1, float& av2)
{
    u32 a0 = rec[0], a1 = rec[1], a2 = rec[2], a3 = rec[3];
    u32 b0 = rec[4], b1 = rec[5], b2 = rec[6];
    // uniform (SGPR) scalars
    float sh0 = lo16(b0), sx = hi16(b0), sy = lo16(b1), sz = hi16(b1);
    // weight contraction: v_fmac with SGPR z operands
    float ws_ = lo16(a0) * fcs[0] + hi16(a0) * fcs[1] + lo16(a1) * fcs[2] + hi16(a1) * fcs[3]
              + lo16(a2) * fcs[4] + hi16(a2) * fcs[5] + lo16(a3) * fcs[6] + hi16(a3) * fcs[7];
    float wv_ = lo16(a0) * fcv[0] + hi16(a0) * fcv[1] + lo16(a1) * fcv[2] + hi16(a1) * fcv[3]
              + lo16(a2) * fcv[4] + hi16(a2) * fcv[5] + lo16(a3) * fcv[6] + hi16(a3) * fcv[7];
    const u16* hp = (const u16*)(hbase + b2);  // SGPR base + lane offset
    float g1 = bfu2f(hp[o1]), g2 = bfu2f(hp[o2]), g3 = bfu2f(hp[o3]);
    // acc_s: D = lo ? g1*sh0 : g1*sx + g2*sy + g3*sz
    float t23 = g2 * sy + g3 * sz;
    t23 = lo ? 0.f : t23;
    float c1 = lo ? sh0 : sx;
    acc_s += ws_ * (g1 * c1 + t23);
    // av_m += A*B_m: A = wv*(lo ? g1 : sh0); B = lo ? (sx,sy,sz) : (g1,g2,g3)
    float A = wv_ * (lo ? g1 : sh0);
    float B0 = lo ? sx : g1;
    float B1 = lo ? sy : g2;
    float B2 = lo ? sz : g3;
    av0 += A * B0; av1 += A * B1; av2 += A * B2;
}

__global__ __launch_bounds__(256) void k2b_gather(
    const u32* __restrict__ edata, const float* __restrict__ fc2,
    const u16* __restrict__ hsv, const int* __restrict__ row_ptr,
    const float* __restrict__ W2s, const float* __restrict__ W2v,
    float* __restrict__ out)
{
    __shared__ float sred[4][256];
    const int tid = threadIdx.x;
    const int wv = tid >> 6, lane = tid & 63;
    const int n = blockIdx.x * 4 + wv;
    const int beg = __builtin_amdgcn_readfirstlane(row_ptr[n]);
    const int end = __builtin_amdgcn_readfirstlane(row_ptr[n + 1]);

    const float inv3 = 0.5773502691896258f;  // 1/sqrt(3)
    const int u = lane & 31;
    const bool lo = lane < 32;
    const int cs = lo ? lane : (96 + u);
    const int cv = lo ? (32 + u) : (64 + u);
    const int o1 = lo ? u : (32 + u);
    const int o2 = lo ? u : (64 + u);
    const int o3 = lo ? u : (96 + u);
    float fcs[8], fcv[8];
#pragma unroll
    for (int j = 0; j < 8; j++) {
        float sscale = lo ? 1.f : inv3;
        fcs[j] = fc2[j * 128 + cs] * sscale;
        fcv[j] = fc2[j * 128 + cv];
    }
    const char* hbase = (const char*)hsv;
    cu32* recbase = (cu32*)(unsigned long long)(const u32*)edata;

    float as[4] = {0.f, 0.f, 0.f, 0.f};
    float a0[4] = {0.f, 0.f, 0.f, 0.f};
    float a1[4] = {0.f, 0.f, 0.f, 0.f};
    float a2[4] = {0.f, 0.f, 0.f, 0.f};
    int s = beg;
    for (; s + 3 < end; s += 4) {
        edge_body(recbase + (size_t)(s + 0) * 8, hbase, fcs, fcv, lo, o1, o2, o3, as[0], a0[0], a1[0], a2[0]);
        edge_body(recbase + (size_t)(s + 1) * 8, hbase, fcs, fcv, lo, o1, o2, o3, as[1], a0[1], a1[1], a2[1]);
        edge_body(recbase + (size_t)(s + 2) * 8, hbase, fcs, fcv, lo, o1, o2, o3, as[2], a0[2], a1[2], a2[2]);
        edge_body(recbase + (size_t)(s + 3) * 8, hbase, fcs, fcv, lo, o1, o2, o3, as[3], a0[3], a1[3], a2[3]);
    }
    for (; s < end; s++)
        edge_body(recbase + (size_t)s * 8, hbase, fcs, fcv, lo, o1, o2, o3, as[0], a0[0], a1[0], a2[0]);
    float acc_s = (as[0] + as[1]) + (as[2] + as[3]);
    float av0 = (a0[0] + a0[1]) + (a0[2] + a0[3]);
    float av1 = (a1[0] + a1[1]) + (a1[2] + a1[3]);
    float av2 = (a2[0] + a2[1]) + (a2[2] + a2[3]);

    // per-wave-private LDS transpose (same wave writes & reads -> no barrier)
    float* red = sred[wv];
    red[lane] = acc_s;               // red[c]        = agg_s[c]
    red[64 + lane * 3 + 0] = av0;    // red[64+3c+m]  = agg_v[c][m]
    red[64 + lane * 3 + 1] = av1;
    red[64 + lane * 3 + 2] = av2;

    // branch-free epilogue: each lane -> 2 dot-64 products
    const float sc2 = 0.03125f;  // inv_n * inv2
    const int w = lane & 31;
    const int b0 = lo ? 0 : 64;
    const int s0 = lo ? 1 : 3;
    const int b1 = lo ? 66 : 65;
    const float* __restrict__ Wp0 = lo ? W2s : W2v;
    float p0 = 0.f, p1 = 0.f;
#pragma unroll 8
    for (int c = 0; c < 64; c++) {
        float r0 = red[b0 + c * s0];
        float r1 = red[b1 + c * 3];
        p0 += r0 * Wp0[c * 32 + w];
        p1 += r1 * W2v[c * 32 + w];
    }
    const size_t o = (size_t)n * 128;
    const int addr0 = lo ? w : (32 + 3 * w);
    const int addr1 = lo ? (32 + 3 * w + 2) : (32 + 3 * w + 1);
    out[o + addr0] += p0 * sc2;
    out[o + addr1] += p1 * sc2;
}

extern "C" void kernel_launch(void* const* d_in, const int* in_sizes, int n_in,
                              void* d_out, int out_size, void* d_ws, size_t ws_size,
                              hipStream_t stream) {
    const float* x    = (const float*)d_in[0];
    const float* h    = (const float*)d_in[1];
    const float* emb  = (const float*)d_in[2];
    const float* esh  = (const float*)d_in[3];
    const int*   eidx = (const int*)d_in[4];
    const float* W1s  = (const float*)d_in[5];
    const float* W1v  = (const float*)d_in[6];
    const float* fc1  = (const float*)d_in[7];
    const float* fc2  = (const float*)d_in[8];
    const float* Wscs = (const float*)d_in[9];
    const float* Wscv = (const float*)d_in[10];
    const float* W2s  = (const float*)d_in[11];
    const float* W2v  = (const float*)d_in[12];
    float* out = (float*)d_out;

    // ws: deg[NN] | row_ptr[NN+1] | cursor[NN] | bsum[196] | pad |
    //     edata u32[EE*8] (25.6MB) | hsv u16[NN*128] (12.8MB) | wscsT/wscvT/w1sT/w1vT
    int* deg      = (int*)d_ws;
    int* row_ptr  = deg + NN;
    int* cursor   = row_ptr + (NN + 1);
    int* bsum     = (int*)d_ws + 150004;
    u32* edata    = (u32*)d_ws + 150208;  // 16B-aligned
    u16* hsv      = (u16*)(edata + (size_t)EE * 8);
    u16* wscsT    = hsv + (size_t)NN * 128;
    u16* wscvT    = wscsT + 16384;
    u16* w1sT     = wscvT + 16384;
    u16* w1vT     = w1sT + 1024;

    hipMemsetAsync(d_ws, 0, (size_t)(3 * NN + 1) * 4, stream);
    k_prep<<<3189, 256, 0, stream>>>(eidx, deg, Wscs, Wscv, W1s, W1v, wscsT, wscvT, w1sT, w1vT);
    k_scan1<<<SCAN_B, 256, 0, stream>>>(deg, bsum);
    k_scan2<<<SCAN_B, 256, 0, stream>>>(deg, bsum, row_ptr);
    k2a1<<<3125 + 391, 256, 0, stream>>>(emb, esh, eidx, fc1, row_ptr, cursor, edata,
                                         x, h, wscsT, wscvT, w1sT, w1vT, hsv, out);
    k2b_gather<<<NN / 4, 256, 0, stream>>>(edata, fc2, hsv, row_ptr, W2s, W2v, out);
}